// Round 3
// baseline (57.788 us; speedup 1.0000x reference)
//
#include <hip/hip_runtime.h>
#include <hip/hip_bf16.h>

#define D 128
#define Nn 512
#define Bb 2

typedef __bf16 bf16x8_t __attribute__((ext_vector_type(8)));
typedef float f32x4_t __attribute__((ext_vector_type(4)));
typedef float f32x8_t __attribute__((ext_vector_type(8)));

// ---------------------------------------------------------------------------
// Kernel 1: A[b,i,e] = (dom*evo)@W1[:D] + b1 ;  C[b,i,e] = (dom*evo)@W1[D:]
// 4 (b,i) rows per block, W1 column stream shared 4-ways.
// Blocks 0..7 additionally emit W2T[e][k] = bf16(W2[k][e])  (64 x 128, 16 KB).
// ---------------------------------------------------------------------------
__global__ __launch_bounds__(256)
void precompute_ac(const float* __restrict__ dom, const float* __restrict__ evo,
                   const float* __restrict__ W1, const float* __restrict__ b1,
                   const float* __restrict__ W2,
                   float* __restrict__ A, float* __restrict__ C,
                   __bf16* __restrict__ W2T) {
    const int t = threadIdx.x;
    const int base = blockIdx.x * 4;
    if (blockIdx.x < 8) {
#pragma unroll
        for (int z = 0; z < 4; ++z) {
            int idx = z * 256 + t;                 // 0..1023
            int e = blockIdx.x * 8 + (idx >> 7);   // 8 e-rows per block
            int k = idx & 127;
            W2T[e * 128 + k] = (__bf16)W2[k * 64 + e];
        }
    }
    __shared__ float g4[4][D];
#pragma unroll
    for (int it = 0; it < 2; ++it) {
        int idx = it * 256 + t;
        int r = idx >> 7, c = idx & 127;
        size_t off = (size_t)(base + r) * D + c;
        g4[r][c] = dom[off] * evo[off];
    }
    __syncthreads();
    const int half = t >> 7;                       // 0 -> A, 1 -> C
    const int e = t & 127;
    const float* Wp = W1 + half * D * D;
    float a0 = 0.f, a1 = 0.f, a2 = 0.f, a3 = 0.f;
#pragma unroll 8
    for (int dp = 0; dp < D; ++dp) {
        float w = Wp[dp * D + e];
        a0 = fmaf(g4[0][dp], w, a0);
        a1 = fmaf(g4[1][dp], w, a1);
        a2 = fmaf(g4[2][dp], w, a2);
        a3 = fmaf(g4[3][dp], w, a3);
    }
    if (half == 0) {
        float bb = b1[e];
        A[(size_t)(base + 0) * D + e] = a0 + bb;
        A[(size_t)(base + 1) * D + e] = a1 + bb;
        A[(size_t)(base + 2) * D + e] = a2 + bb;
        A[(size_t)(base + 3) * D + e] = a3 + bb;
    } else {
        C[(size_t)(base + 0) * D + e] = a0;
        C[(size_t)(base + 1) * D + e] = a1;
        C[(size_t)(base + 2) * D + e] = a2;
        C[(size_t)(base + 3) * D + e] = a3;
    }
}

// ---------------------------------------------------------------------------
// Kernel 2: grid = exactly the active (b, i-group-4, j-chunk-64) units (1152).
// No LDS, no barriers: 4 independent waves, wave = one i, C/W2T read from L2.
// Writes UPPER triangle only (full-line row segments). Diagonal = 0.
// Unit index u (per batch, 576): chunk c start offset = 8c(c+1), g in [0,16(c+1)).
// ---------------------------------------------------------------------------
__global__ __launch_bounds__(256, 4)
void coevo_main(const float* __restrict__ A, const float* __restrict__ Cm,
                const __bf16* __restrict__ W2T, const float* __restrict__ b2,
                const float* __restrict__ W3, const float* __restrict__ b3,
                float* __restrict__ out) {
    const int tid  = threadIdx.x;
    const int wave = tid >> 6;
    const int lane = tid & 63;
    const int m = lane & 15;
    const int q = lane >> 4;

    int u = blockIdx.x;
    const int b = (u >= 576) ? 1 : 0;
    u -= b * 576;
    int chunk = 0;
#pragma unroll
    for (int cc = 1; cc < 8; ++cc) if (u >= 8 * cc * (cc + 1)) chunk = cc;
    const int g = u - 8 * chunk * (chunk + 1);     // 0 .. 16*(chunk+1)-1
    const int i = g * 4 + wave;

    // ---- per-lane A row (b1 folded): abv[kk][e] = A[b,i, kk*32 + q*8 + e]
    f32x8_t abv[4];
    {
        const float* Ap = A + ((size_t)(b * Nn + i)) * D + q * 8;
#pragma unroll
        for (int kk = 0; kk < 4; ++kk) {
            f32x4_t v0 = *(const f32x4_t*)(Ap + kk * 32);
            f32x4_t v1 = *(const f32x4_t*)(Ap + kk * 32 + 4);
            f32x8_t v;
            v[0] = v0[0]; v[1] = v0[1]; v[2] = v0[2]; v[3] = v0[3];
            v[4] = v1[0]; v[5] = v1[1]; v[6] = v1[2]; v[7] = v1[3];
            abv[kk] = v;
        }
    }

    // ---- W2 B-fragments: one 16B load each from pre-transposed W2T (L2-hot)
    bf16x8_t w2f[4][4];
#pragma unroll
    for (int et = 0; et < 4; ++et)
#pragma unroll
        for (int kk = 0; kk < 4; ++kk)
            w2f[et][kk] = *(const bf16x8_t*)(W2T + (et * 16 + m) * 128 + kk * 32 + q * 8);

    // ---- epilogue constants for this lane's columns e = et*16 + m
    float b2v[4], w3v[4];
#pragma unroll
    for (int et = 0; et < 4; ++et) {
        b2v[et] = b2[et * 16 + m];
        w3v[et] = W3[et * 16 + m];
    }
    const float b3s = b3[0];

    // this lane's j-row base within the chunk: j = chunk*64 + jt*16 + m
    const float* Cbase = Cm + ((size_t)b * Nn + (size_t)chunk * 64 + m) * D + q * 8;

#pragma unroll
    for (int jt = 0; jt < 4; ++jt) {
        if (chunk * 64 + jt * 16 + 15 < i) continue;   // tile entirely below diag
        const float* cp = Cbase + (size_t)jt * 16 * D;

        // ---- build H fragments: h = relu(a + c)  (packed f32 ops + cvt_pk)
        bf16x8_t af[4];
#pragma unroll
        for (int kk = 0; kk < 4; ++kk) {
            f32x4_t c0 = *(const f32x4_t*)(cp + kk * 32);
            f32x4_t c1 = *(const f32x4_t*)(cp + kk * 32 + 4);
            f32x8_t t8 = abv[kk];
            t8[0] += c0[0]; t8[1] += c0[1]; t8[2] += c0[2]; t8[3] += c0[3];
            t8[4] += c1[0]; t8[5] += c1[1]; t8[6] += c1[2]; t8[7] += c1[3];
            t8 = __builtin_elementwise_max(t8, (f32x8_t)0.f);
            af[kk] = __builtin_convertvector(t8, bf16x8_t);
        }

        // ---- GEMM: [16j x 128k] @ [128k x 64e]
        f32x4_t acc[4];
#pragma unroll
        for (int et = 0; et < 4; ++et) {
            f32x4_t a = {0.f, 0.f, 0.f, 0.f};
#pragma unroll
            for (int kk = 0; kk < 4; ++kk)
                a = __builtin_amdgcn_mfma_f32_16x16x32_bf16(af[kk], w2f[et][kk], a, 0, 0, 0);
            acc[et] = a;
        }

        // ---- epilogue: relu(+b2), dot W3 over e, 16-lane reduce, sigmoid
        float part[4];
#pragma unroll
        for (int r = 0; r < 4; ++r) {
            float p = 0.f;
#pragma unroll
            for (int et = 0; et < 4; ++et) {
                float h2 = fmaxf(acc[et][r] + b2v[et], 0.f);
                p = fmaf(h2, w3v[et], p);
            }
            part[r] = p;
        }
#pragma unroll
        for (int off = 8; off >= 1; off >>= 1) {
#pragma unroll
            for (int r = 0; r < 4; ++r)
                part[r] += __shfl_xor(part[r], off, 64);
        }

        if (m == 0) {
            const int j0 = chunk * 64 + jt * 16 + q * 4;
#pragma unroll
            for (int r = 0; r < 4; ++r) {
                const int j = j0 + r;
                if (j > i) {
                    float sv = 1.f / (1.f + expf(-(part[r] + b3s)));
                    out[((size_t)b * Nn + i) * Nn + j] = sv;
                } else if (j == i) {
                    out[((size_t)b * Nn + i) * Nn + j] = 0.f;
                }
            }
        }
    }
}

// ---------------------------------------------------------------------------
// Kernel 3: fill strictly-lower triangle from the upper one, 64x64 LDS tiles.
// Coalesced full-line reads AND writes. 36 tiles/batch (R >= C).
// ---------------------------------------------------------------------------
__global__ __launch_bounds__(256)
void mirror_lower(float* __restrict__ out) {
    const int t = threadIdx.x;
    int u = blockIdx.x;
    const int b = (u >= 36) ? 1 : 0;
    u -= b * 36;
    int R = 0;
#pragma unroll
    for (int rr = 1; rr < 8; ++rr) if (u >= rr * (rr + 1) / 2) R = rr;
    const int Cc = u - R * (R + 1) / 2;            // Cc <= R

    __shared__ float ts[64 * 65];
    float* ob = out + (size_t)b * Nn * Nn;

    // load source tile: rows Cc*64+sr (upper side), cols R*64+sc
#pragma unroll
    for (int it = 0; it < 4; ++it) {
        int f = it * 256 + t;                      // f32x4 unit 0..1023
        int sr = f >> 4, sc = (f & 15) * 4;
        f32x4_t v = *(const f32x4_t*)(ob + (size_t)(Cc * 64 + sr) * Nn + R * 64 + sc);
        ts[sr * 65 + sc + 0] = v[0];
        ts[sr * 65 + sc + 1] = v[1];
        ts[sr * 65 + sc + 2] = v[2];
        ts[sr * 65 + sc + 3] = v[3];
    }
    __syncthreads();
    // write dest tile: rows R*64+dr, cols Cc*64+dc  (transposed from LDS)
#pragma unroll
    for (int it = 0; it < 4; ++it) {
        int f = it * 256 + t;
        int dr = f >> 4, dc = (f & 15) * 4;
        float v0 = ts[(dc + 0) * 65 + dr];
        float v1 = ts[(dc + 1) * 65 + dr];
        float v2 = ts[(dc + 2) * 65 + dr];
        float v3 = ts[(dc + 3) * 65 + dr];
        size_t o = (size_t)(R * 64 + dr) * Nn + Cc * 64 + dc;
        if (R != Cc) {
            f32x4_t v; v[0] = v0; v[1] = v1; v[2] = v2; v[3] = v3;
            *(f32x4_t*)(ob + o) = v;
        } else {                                   // diagonal tile: dr > dc+z only
            if (dr > dc + 0) ob[o + 0] = v0;
            if (dr > dc + 1) ob[o + 1] = v1;
            if (dr > dc + 2) ob[o + 2] = v2;
            if (dr > dc + 3) ob[o + 3] = v3;
        }
    }
}

extern "C" void kernel_launch(void* const* d_in, const int* in_sizes, int n_in,
                              void* d_out, int out_size, void* d_ws, size_t ws_size,
                              hipStream_t stream) {
    const float* dom = (const float*)d_in[0];
    const float* evo = (const float*)d_in[1];
    const float* W1  = (const float*)d_in[2];
    const float* b1  = (const float*)d_in[3];
    const float* W2  = (const float*)d_in[4];
    const float* b2  = (const float*)d_in[5];
    const float* W3  = (const float*)d_in[6];
    const float* b3  = (const float*)d_in[7];
    float* out = (float*)d_out;

    float* A  = (float*)d_ws;                      // [B][N][D] f32
    float* C  = A + (size_t)Bb * Nn * D;           // [B][N][D] f32
    __bf16* W2T = (__bf16*)(C + (size_t)Bb * Nn * D);   // [64][128] bf16

    precompute_ac<<<Bb * Nn / 4, 256, 0, stream>>>(dom, evo, W1, b1, W2, A, C, W2T);
    coevo_main<<<Bb * 576, 256, 0, stream>>>(A, C, W2T, b2, W3, b3, out);
    mirror_lower<<<Bb * 36, 256, 0, stream>>>(out);
}

// Round 4
// 31.952 us; speedup vs baseline: 1.8086x; 1.8086x over previous
//
#include <hip/hip_runtime.h>
#include <hip/hip_bf16.h>

#define D 128
#define Nn 512
#define Bb 2

typedef __bf16 bf16x8_t __attribute__((ext_vector_type(8)));
typedef float f32x4_t __attribute__((ext_vector_type(4)));
typedef float f32x8_t __attribute__((ext_vector_type(8)));

// ---------------------------------------------------------------------------
// Kernel 1: A[b,i,e] = (dom*evo)@W1[:D] + b1 ;  C[b,i,e] = (dom*evo)@W1[D:]
// 4 (b,i) rows per block, W1 column stream shared 4-ways.
// Blocks 0..7 additionally emit W2T[e][k] = bf16(W2[k][e])  (64 x 128, 16 KB).
// ---------------------------------------------------------------------------
__global__ __launch_bounds__(256)
void precompute_ac(const float* __restrict__ dom, const float* __restrict__ evo,
                   const float* __restrict__ W1, const float* __restrict__ b1,
                   const float* __restrict__ W2,
                   float* __restrict__ A, float* __restrict__ C,
                   __bf16* __restrict__ W2T) {
    const int t = threadIdx.x;
    const int base = blockIdx.x * 4;
    if (blockIdx.x < 8) {
#pragma unroll
        for (int z = 0; z < 4; ++z) {
            int idx = z * 256 + t;                 // 0..1023
            int e = blockIdx.x * 8 + (idx >> 7);   // 8 e-rows per block
            int k = idx & 127;
            W2T[e * 128 + k] = (__bf16)W2[k * 64 + e];
        }
    }
    __shared__ float g4[4][D];
#pragma unroll
    for (int it = 0; it < 2; ++it) {
        int idx = it * 256 + t;
        int r = idx >> 7, c = idx & 127;
        size_t off = (size_t)(base + r) * D + c;
        g4[r][c] = dom[off] * evo[off];
    }
    __syncthreads();
    const int half = t >> 7;                       // 0 -> A, 1 -> C
    const int e = t & 127;
    const float* Wp = W1 + half * D * D;
    float a0 = 0.f, a1 = 0.f, a2 = 0.f, a3 = 0.f;
#pragma unroll 8
    for (int dp = 0; dp < D; ++dp) {
        float w = Wp[dp * D + e];
        a0 = fmaf(g4[0][dp], w, a0);
        a1 = fmaf(g4[1][dp], w, a1);
        a2 = fmaf(g4[2][dp], w, a2);
        a3 = fmaf(g4[3][dp], w, a3);
    }
    if (half == 0) {
        float bb = b1[e];
        A[(size_t)(base + 0) * D + e] = a0 + bb;
        A[(size_t)(base + 1) * D + e] = a1 + bb;
        A[(size_t)(base + 2) * D + e] = a2 + bb;
        A[(size_t)(base + 3) * D + e] = a3 + bb;
    } else {
        C[(size_t)(base + 0) * D + e] = a0;
        C[(size_t)(base + 1) * D + e] = a1;
        C[(size_t)(base + 2) * D + e] = a2;
        C[(size_t)(base + 3) * D + e] = a3;
    }
}

// ---------------------------------------------------------------------------
// Kernel 2: grid = exactly the active (b, i-group-4, j-chunk-64) units (1152).
// 4 waves, wave = one i.  C-chunk (32KB f32) and W2T (16KB bf16) staged in LDS
// once per block, XOR-swizzled in 16B granules (key = row&7) so the m-strided
// ds_read_b128 is <=2-way (free).  W2 fragments live in registers across jt.
// __launch_bounds__(256,3): VGPR cap 168 so nothing is rematerialized.
// Writes UPPER triangle only. Diagonal = 0.
// ---------------------------------------------------------------------------
__global__ __launch_bounds__(256, 3)
void coevo_main(const float* __restrict__ A, const float* __restrict__ Cm,
                const __bf16* __restrict__ W2T, const float* __restrict__ b2,
                const float* __restrict__ W3, const float* __restrict__ b3,
                float* __restrict__ out) {
    const int tid  = threadIdx.x;
    const int wave = tid >> 6;
    const int lane = tid & 63;
    const int m = lane & 15;
    const int q = lane >> 4;

    int u = blockIdx.x;
    const int b = (u >= 576) ? 1 : 0;
    u -= b * 576;
    int chunk = 0;
#pragma unroll
    for (int cc = 1; cc < 8; ++cc) if (u >= 8 * cc * (cc + 1)) chunk = cc;
    const int g = u - 8 * chunk * (chunk + 1);     // 0 .. 16*(chunk+1)-1
    const int i = g * 4 + wave;

    __shared__ float  cs[64 * 128];                // 32 KB, swizzled 16B granules
    __shared__ __bf16 w2s[64 * 128];               // 16 KB, swizzled 16B granules

    // ---- stage C chunk: 2048 granules, 8 per thread
    const float* Cb = Cm + ((size_t)b * Nn + (size_t)chunk * 64) * D;
    f32x4_t* csv = (f32x4_t*)cs;
#pragma unroll
    for (int it = 0; it < 8; ++it) {
        int f = it * 256 + tid;                    // granule idx
        int r = f >> 5, g4 = f & 31;
        csv[r * 32 + (g4 ^ (r & 7))] = *(const f32x4_t*)(Cb + (size_t)f * 4);
    }
    // ---- stage W2T: 1024 granules, 4 per thread
    f32x4_t* w2v = (f32x4_t*)w2s;
    const f32x4_t* W2Tg = (const f32x4_t*)W2T;
#pragma unroll
    for (int it = 0; it < 4; ++it) {
        int f = it * 256 + tid;
        int r = f >> 4, g4 = f & 15;
        w2v[r * 16 + (g4 ^ (r & 7))] = W2Tg[f];
    }

    // ---- per-lane A row (b1 folded): abv[kk][e] = A[b,i, kk*32 + q*8 + e]
    f32x8_t abv[4];
    {
        const float* Ap = A + ((size_t)(b * Nn + i)) * D + q * 8;
#pragma unroll
        for (int kk = 0; kk < 4; ++kk) {
            f32x4_t v0 = *(const f32x4_t*)(Ap + kk * 32);
            f32x4_t v1 = *(const f32x4_t*)(Ap + kk * 32 + 4);
            f32x8_t v;
            v[0] = v0[0]; v[1] = v0[1]; v[2] = v0[2]; v[3] = v0[3];
            v[4] = v1[0]; v[5] = v1[1]; v[6] = v1[2]; v[7] = v1[3];
            abv[kk] = v;
        }
    }

    // ---- epilogue constants for this lane's columns e = et*16 + m
    float b2v[4], w3v[4];
#pragma unroll
    for (int et = 0; et < 4; ++et) {
        b2v[et] = b2[et * 16 + m];
        w3v[et] = W3[et * 16 + m];
    }
    const float b3s = b3[0];
    const int key = m & 7;

    __syncthreads();

    // ---- W2 B-fragments from LDS, held in registers for the whole jt loop
    bf16x8_t w2f[4][4];
    const bf16x8_t* w2r = (const bf16x8_t*)w2s;
#pragma unroll
    for (int et = 0; et < 4; ++et)
#pragma unroll
        for (int kk = 0; kk < 4; ++kk)
            w2f[et][kk] = w2r[(et * 16 + m) * 16 + ((kk * 4 + q) ^ key)];

#pragma unroll
    for (int jt = 0; jt < 4; ++jt) {
        if (chunk * 64 + jt * 16 + 15 < i) continue;   // tile entirely below diag
        const f32x4_t* crow = (const f32x4_t*)cs + (size_t)(jt * 16 + m) * 32;

        // ---- build H fragments: h = relu(a + c)  (packed f32 ops)
        bf16x8_t af[4];
#pragma unroll
        for (int kk = 0; kk < 4; ++kk) {
            const int g0 = kk * 8 + q * 2;
            f32x4_t c0 = crow[g0 ^ key];
            f32x4_t c1 = crow[(g0 + 1) ^ key];
            f32x8_t c8;
            c8[0] = c0[0]; c8[1] = c0[1]; c8[2] = c0[2]; c8[3] = c0[3];
            c8[4] = c1[0]; c8[5] = c1[1]; c8[6] = c1[2]; c8[7] = c1[3];
            f32x8_t t8 = __builtin_elementwise_max(abv[kk] + c8, (f32x8_t)0.f);
            af[kk] = __builtin_convertvector(t8, bf16x8_t);
        }

        // ---- GEMM: [16j x 128k] @ [128k x 64e]
        f32x4_t acc[4];
#pragma unroll
        for (int et = 0; et < 4; ++et) {
            f32x4_t a = {0.f, 0.f, 0.f, 0.f};
#pragma unroll
            for (int kk = 0; kk < 4; ++kk)
                a = __builtin_amdgcn_mfma_f32_16x16x32_bf16(af[kk], w2f[et][kk], a, 0, 0, 0);
            acc[et] = a;
        }

        // ---- epilogue: relu(+b2), dot W3 over e, 16-lane reduce, sigmoid
        float part[4];
#pragma unroll
        for (int r = 0; r < 4; ++r) {
            float p = 0.f;
#pragma unroll
            for (int et = 0; et < 4; ++et) {
                float h2 = fmaxf(acc[et][r] + b2v[et], 0.f);
                p = fmaf(h2, w3v[et], p);
            }
            part[r] = p;
        }
#pragma unroll
        for (int off = 8; off >= 1; off >>= 1) {
#pragma unroll
            for (int r = 0; r < 4; ++r)
                part[r] += __shfl_xor(part[r], off, 64);
        }

        if (m == 0) {
            const int j0 = chunk * 64 + jt * 16 + q * 4;
#pragma unroll
            for (int r = 0; r < 4; ++r) {
                const int j = j0 + r;
                if (j > i) {
                    float sv = 1.f / (1.f + expf(-(part[r] + b3s)));
                    out[((size_t)b * Nn + i) * Nn + j] = sv;
                } else if (j == i) {
                    out[((size_t)b * Nn + i) * Nn + j] = 0.f;
                }
            }
        }
    }
}

// ---------------------------------------------------------------------------
// Kernel 3: fill strictly-lower triangle from the upper one, 64x64 LDS tiles.
// Coalesced full-line reads AND writes. 36 tiles/batch (R >= C).
// ---------------------------------------------------------------------------
__global__ __launch_bounds__(256)
void mirror_lower(float* __restrict__ out) {
    const int t = threadIdx.x;
    int u = blockIdx.x;
    const int b = (u >= 36) ? 1 : 0;
    u -= b * 36;
    int R = 0;
#pragma unroll
    for (int rr = 1; rr < 8; ++rr) if (u >= rr * (rr + 1) / 2) R = rr;
    const int Cc = u - R * (R + 1) / 2;            // Cc <= R

    __shared__ float ts[64 * 65];
    float* ob = out + (size_t)b * Nn * Nn;

#pragma unroll
    for (int it = 0; it < 4; ++it) {
        int f = it * 256 + t;
        int sr = f >> 4, sc = (f & 15) * 4;
        f32x4_t v = *(const f32x4_t*)(ob + (size_t)(Cc * 64 + sr) * Nn + R * 64 + sc);
        ts[sr * 65 + sc + 0] = v[0];
        ts[sr * 65 + sc + 1] = v[1];
        ts[sr * 65 + sc + 2] = v[2];
        ts[sr * 65 + sc + 3] = v[3];
    }
    __syncthreads();
#pragma unroll
    for (int it = 0; it < 4; ++it) {
        int f = it * 256 + t;
        int dr = f >> 4, dc = (f & 15) * 4;
        float v0 = ts[(dc + 0) * 65 + dr];
        float v1 = ts[(dc + 1) * 65 + dr];
        float v2 = ts[(dc + 2) * 65 + dr];
        float v3 = ts[(dc + 3) * 65 + dr];
        size_t o = (size_t)(R * 64 + dr) * Nn + Cc * 64 + dc;
        if (R != Cc) {
            f32x4_t v; v[0] = v0; v[1] = v1; v[2] = v2; v[3] = v3;
            *(f32x4_t*)(ob + o) = v;
        } else {
            if (dr > dc + 0) ob[o + 0] = v0;
            if (dr > dc + 1) ob[o + 1] = v1;
            if (dr > dc + 2) ob[o + 2] = v2;
            if (dr > dc + 3) ob[o + 3] = v3;
        }
    }
}

extern "C" void kernel_launch(void* const* d_in, const int* in_sizes, int n_in,
                              void* d_out, int out_size, void* d_ws, size_t ws_size,
                              hipStream_t stream) {
    const float* dom = (const float*)d_in[0];
    const float* evo = (const float*)d_in[1];
    const float* W1  = (const float*)d_in[2];
    const float* b1  = (const float*)d_in[3];
    const float* W2  = (const float*)d_in[4];
    const float* b2  = (const float*)d_in[5];
    const float* W3  = (const float*)d_in[6];
    const float* b3  = (const float*)d_in[7];
    float* out = (float*)d_out;

    float* A  = (float*)d_ws;                      // [B][N][D] f32
    float* C  = A + (size_t)Bb * Nn * D;           // [B][N][D] f32
    __bf16* W2T = (__bf16*)(C + (size_t)Bb * Nn * D);   // [64][128] bf16

    precompute_ac<<<Bb * Nn / 4, 256, 0, stream>>>(dom, evo, W1, b1, W2, A, C, W2T);
    coevo_main<<<Bb * 576, 256, 0, stream>>>(A, C, W2T, b2, W3, b3, out);
    mirror_lower<<<Bb * 36, 256, 0, stream>>>(out);
}

// Round 5
// 26.228 us; speedup vs baseline: 2.2033x; 1.2182x over previous
//
#include <hip/hip_runtime.h>
#include <hip/hip_bf16.h>

#define D 128
#define Nn 512
#define Bb 2

typedef __bf16 bf16x8_t __attribute__((ext_vector_type(8)));
typedef unsigned short u16x8_t __attribute__((ext_vector_type(8)));
typedef float f32x4_t __attribute__((ext_vector_type(4)));
typedef float f32x8_t __attribute__((ext_vector_type(8)));

// ---------------------------------------------------------------------------
// Kernel 1: A[b,i,e] = (dom*evo)@W1[:D] + b1  (f32);  Cb[b,i,e] = (dom*evo)@W1[D:]
// stored in bf16.  4 rows per block, W1 column stream shared 4-ways.
// Blocks 0..7 additionally emit W2T[e][k] = bf16(W2[k][e])  (64 x 128, 16 KB).
// ---------------------------------------------------------------------------
__global__ __launch_bounds__(256)
void precompute_ac(const float* __restrict__ dom, const float* __restrict__ evo,
                   const float* __restrict__ W1, const float* __restrict__ b1,
                   const float* __restrict__ W2,
                   float* __restrict__ A, __bf16* __restrict__ Cb,
                   __bf16* __restrict__ W2T) {
    const int t = threadIdx.x;
    const int base = blockIdx.x * 4;
    if (blockIdx.x < 8) {
#pragma unroll
        for (int z = 0; z < 4; ++z) {
            int idx = z * 256 + t;                 // 0..1023
            int e = blockIdx.x * 8 + (idx >> 7);   // 8 e-rows per block
            int k = idx & 127;
            W2T[e * 128 + k] = (__bf16)W2[k * 64 + e];
        }
    }
    __shared__ float g4[4][D];
#pragma unroll
    for (int it = 0; it < 2; ++it) {
        int idx = it * 256 + t;
        int r = idx >> 7, c = idx & 127;
        size_t off = (size_t)(base + r) * D + c;
        g4[r][c] = dom[off] * evo[off];
    }
    __syncthreads();
    const int half = t >> 7;                       // 0 -> A, 1 -> C
    const int e = t & 127;
    const float* Wp = W1 + half * D * D;
    float a0 = 0.f, a1 = 0.f, a2 = 0.f, a3 = 0.f;
#pragma unroll 8
    for (int dp = 0; dp < D; ++dp) {
        float w = Wp[dp * D + e];
        a0 = fmaf(g4[0][dp], w, a0);
        a1 = fmaf(g4[1][dp], w, a1);
        a2 = fmaf(g4[2][dp], w, a2);
        a3 = fmaf(g4[3][dp], w, a3);
    }
    if (half == 0) {
        float bb = b1[e];
        A[(size_t)(base + 0) * D + e] = a0 + bb;
        A[(size_t)(base + 1) * D + e] = a1 + bb;
        A[(size_t)(base + 2) * D + e] = a2 + bb;
        A[(size_t)(base + 3) * D + e] = a3 + bb;
    } else {
        Cb[(size_t)(base + 0) * D + e] = (__bf16)a0;
        Cb[(size_t)(base + 1) * D + e] = (__bf16)a1;
        Cb[(size_t)(base + 2) * D + e] = (__bf16)a2;
        Cb[(size_t)(base + 3) * D + e] = (__bf16)a3;
    }
}

// ---------------------------------------------------------------------------
// Kernel 2: grid = exactly the active (b, i-group-4, j-chunk-64) units (1152).
// 4 waves, wave = one i.  C-chunk (16KB bf16) + W2T (16KB bf16) staged in LDS,
// XOR-swizzled in 16B granules (key = row&15) -> even bank spread.
// Per jt: build H frags once; et-loop reloads W2 frags from LDS (low VGPR).
// Block output tile (4 i x 64 j) accumulated in LDS, then written BOTH as
// coalesced upper rows and 16B-segment mirrored lower columns. Diagonal = 0.
// LDS 33KB + ~100 VGPR -> 4 blocks/CU (16 waves).
// ---------------------------------------------------------------------------
__global__ __launch_bounds__(256, 4)
void coevo_main(const float* __restrict__ A, const __bf16* __restrict__ Cm,
                const __bf16* __restrict__ W2T, const float* __restrict__ b2,
                const float* __restrict__ W3, const float* __restrict__ b3,
                float* __restrict__ out) {
    const int tid  = threadIdx.x;
    const int wave = tid >> 6;
    const int lane = tid & 63;
    const int m = lane & 15;
    const int q = lane >> 4;

    int u = blockIdx.x;
    const int b = (u >= 576) ? 1 : 0;
    u -= b * 576;
    int chunk = 0;
#pragma unroll
    for (int cc = 1; cc < 8; ++cc) if (u >= 8 * cc * (cc + 1)) chunk = cc;
    const int g = u - 8 * chunk * (chunk + 1);     // 0 .. 16*(chunk+1)-1
    const int i = g * 4 + wave;
    const int i0 = g * 4;

    __shared__ __bf16 cs[64 * 128];                // 16 KB, swizzled
    __shared__ __bf16 w2s[64 * 128];               // 16 KB, swizzled
    __shared__ float  tile[4][64];                 // block output tile

    // ---- stage C chunk (bf16): 1024 granules of 16B, 4 per thread
    const f32x4_t* Cg = (const f32x4_t*)(Cm + ((size_t)b * Nn + (size_t)chunk * 64) * D);
    f32x4_t* csv = (f32x4_t*)cs;
#pragma unroll
    for (int it = 0; it < 4; ++it) {
        int f = it * 256 + tid;
        int r = f >> 4, gi = f & 15;
        csv[r * 16 + (gi ^ (r & 15))] = Cg[f];
    }
    // ---- stage W2T: 1024 granules, 4 per thread
    f32x4_t* w2v = (f32x4_t*)w2s;
    const f32x4_t* W2Tg = (const f32x4_t*)W2T;
#pragma unroll
    for (int it = 0; it < 4; ++it) {
        int f = it * 256 + tid;
        int r = f >> 4, gi = f & 15;
        w2v[r * 16 + (gi ^ (r & 15))] = W2Tg[f];
    }

    // ---- per-lane A row (b1 folded): abv[kk][e] = A[b,i, kk*32 + q*8 + e]
    f32x8_t abv[4];
    {
        const float* Ap = A + ((size_t)(b * Nn + i)) * D + q * 8;
#pragma unroll
        for (int kk = 0; kk < 4; ++kk) {
            f32x4_t v0 = *(const f32x4_t*)(Ap + kk * 32);
            f32x4_t v1 = *(const f32x4_t*)(Ap + kk * 32 + 4);
            f32x8_t v;
            v[0] = v0[0]; v[1] = v0[1]; v[2] = v0[2]; v[3] = v0[3];
            v[4] = v1[0]; v[5] = v1[1]; v[6] = v1[2]; v[7] = v1[3];
            abv[kk] = v;
        }
    }

    // ---- epilogue constants for this lane's columns e = et*16 + m
    float b2v[4], w3v[4];
#pragma unroll
    for (int et = 0; et < 4; ++et) {
        b2v[et] = b2[et * 16 + m];
        w3v[et] = W3[et * 16 + m];
    }
    const float b3s = b3[0];

    __syncthreads();

    const u16x8_t* csr  = (const u16x8_t*)cs;
    const bf16x8_t* w2r = (const bf16x8_t*)w2s;

#pragma unroll
    for (int jt = 0; jt < 4; ++jt) {
        if (chunk * 64 + jt * 16 + 15 < i) continue;   // tile entirely below diag
        const int r0  = jt * 16 + m;                   // this lane's j row
        const int key = r0 & 15;

        // ---- build H fragments: h = relu(a + c), c expanded from bf16
        bf16x8_t af[4];
#pragma unroll
        for (int kk = 0; kk < 4; ++kk) {
            u16x8_t cr = csr[r0 * 16 + ((kk * 4 + q) ^ key)];
            f32x8_t c8;
#pragma unroll
            for (int z = 0; z < 8; ++z)
                c8[z] = __builtin_bit_cast(float, (unsigned)cr[z] << 16);
            f32x8_t t8 = __builtin_elementwise_max(abv[kk] + c8, (f32x8_t)0.f);
            af[kk] = __builtin_convertvector(t8, bf16x8_t);
        }

        // ---- GEMM + epilogue fused per et (keeps acc at 4 VGPR)
        float part[4] = {0.f, 0.f, 0.f, 0.f};
#pragma unroll
        for (int et = 0; et < 4; ++et) {
            bf16x8_t wf[4];
#pragma unroll
            for (int kk = 0; kk < 4; ++kk)
                wf[kk] = w2r[(et * 16 + m) * 16 + ((kk * 4 + q) ^ m)];
            f32x4_t a = {0.f, 0.f, 0.f, 0.f};
#pragma unroll
            for (int kk = 0; kk < 4; ++kk)
                a = __builtin_amdgcn_mfma_f32_16x16x32_bf16(af[kk], wf[kk], a, 0, 0, 0);
#pragma unroll
            for (int r = 0; r < 4; ++r)
                part[r] = fmaf(fmaxf(a[r] + b2v[et], 0.f), w3v[et], part[r]);
        }

        // ---- reduce over the 16 e-lanes (m), sigmoid, park in tile
#pragma unroll
        for (int off = 8; off >= 1; off >>= 1) {
#pragma unroll
            for (int r = 0; r < 4; ++r)
                part[r] += __shfl_xor(part[r], off, 64);
        }
        if (m == 0) {
#pragma unroll
            for (int r = 0; r < 4; ++r) {
                int jc = jt * 16 + q * 4 + r;      // col within chunk
                tile[wave][jc] = 1.f / (1.f + expf(-(part[r] + b3s)));
            }
        }
    }

    __syncthreads();

    // ---- upper store: row i, 64 cols (coalesced f32x4), diag = 0
    if ((tid & 63) < 16) {
        const int c4 = tid & 15;
        const int j0 = chunk * 64 + c4 * 4;
        float v0 = tile[wave][c4 * 4 + 0];
        float v1 = tile[wave][c4 * 4 + 1];
        float v2 = tile[wave][c4 * 4 + 2];
        float v3 = tile[wave][c4 * 4 + 3];
        float* op = out + ((size_t)b * Nn + i) * Nn + j0;
        if (j0 > i) {
            f32x4_t v; v[0] = v0; v[1] = v1; v[2] = v2; v[3] = v3;
            *(f32x4_t*)op = v;
        } else if (j0 + 3 >= i) {                  // straddles diagonal
            if (j0 + 0 > i) op[0] = v0; else if (j0 + 0 == i) op[0] = 0.f;
            if (j0 + 1 > i) op[1] = v1; else if (j0 + 1 == i) op[1] = 0.f;
            if (j0 + 2 > i) op[2] = v2; else if (j0 + 2 == i) op[2] = 0.f;
            if (j0 + 3 > i) op[3] = v3; else if (j0 + 3 == i) op[3] = 0.f;
        }                                          // else fully below diag: skip
    }
    // ---- lower (mirror) store: 64 rows j, cols i0..i0+3 (16B segments)
    if (tid < 64) {
        const int j = chunk * 64 + tid;
        float v0 = tile[0][tid], v1 = tile[1][tid], v2 = tile[2][tid], v3 = tile[3][tid];
        float* op = out + ((size_t)b * Nn + j) * Nn + i0;
        if (j > i0 + 3) {
            f32x4_t v; v[0] = v0; v[1] = v1; v[2] = v2; v[3] = v3;
            *(f32x4_t*)op = v;
        } else {
            if (j > i0 + 0) op[0] = v0;
            if (j > i0 + 1) op[1] = v1;
            if (j > i0 + 2) op[2] = v2;
            if (j > i0 + 3) op[3] = v3;
        }
    }
}

extern "C" void kernel_launch(void* const* d_in, const int* in_sizes, int n_in,
                              void* d_out, int out_size, void* d_ws, size_t ws_size,
                              hipStream_t stream) {
    const float* dom = (const float*)d_in[0];
    const float* evo = (const float*)d_in[1];
    const float* W1  = (const float*)d_in[2];
    const float* b1  = (const float*)d_in[3];
    const float* W2  = (const float*)d_in[4];
    const float* b2  = (const float*)d_in[5];
    const float* W3  = (const float*)d_in[6];
    const float* b3  = (const float*)d_in[7];
    float* out = (float*)d_out;

    float*  A   = (float*)d_ws;                          // [B][N][D] f32 (512 KB)
    __bf16* Cb  = (__bf16*)(A + (size_t)Bb * Nn * D);    // [B][N][D] bf16 (256 KB)
    __bf16* W2T = Cb + (size_t)Bb * Nn * D;              // [64][128] bf16 (16 KB)

    precompute_ac<<<Bb * Nn / 4, 256, 0, stream>>>(dom, evo, W1, b1, W2, A, Cb, W2T);
    coevo_main<<<Bb * 576, 256, 0, stream>>>(A, Cb, W2T, b2, W3, b3, out);
}